// Round 7
// baseline (546.085 us; speedup 1.0000x reference)
//
#include <hip/hip_runtime.h>
#include <math.h>

#define MD   512
#define NH   8
#define DH   64
#define SEQ  4096
#define NSPLIT 4
#define KEYS_PER_SPLIT (SEQ / NSPLIT)   // 1024

typedef _Float16 f16x8 __attribute__((ext_vector_type(8)));
typedef _Float16 f16x4 __attribute__((ext_vector_type(4)));
typedef float    f32x4 __attribute__((ext_vector_type(4)));

#define LDSTR 72   // f16 row stride: 144 B, 16B-aligned, 2-way bank aliasing max

// ---------------------------------------------------------------- weight transpose (hi only), 4 weights fused
__global__ __launch_bounds__(256)
void trans4(const float* __restrict__ w0, const float* __restrict__ w1,
            const float* __restrict__ w2, const float* __restrict__ w3,
            _Float16* __restrict__ wt, size_t WK)
{
    const int z = blockIdx.z;
    const float* in = (z == 0) ? w0 : (z == 1) ? w1 : (z == 2) ? w2 : w3;
    _Float16* oh = wt + (size_t)z * WK;

    __shared__ float T[64][68];
    const int r0 = blockIdx.x * 64;
    const int c0 = blockIdx.y * 64;
    const int r  = threadIdx.x >> 2;
    const int cb = (threadIdx.x & 3) << 4;

#pragma unroll
    for (int it = 0; it < 4; ++it) {
        const float4 x = *(const float4*)&in[(size_t)(r0 + r) * MD + c0 + cb + (it << 2)];
        *(float4*)&T[r][cb + (it << 2)] = x;
    }
    __syncthreads();

#pragma unroll
    for (int hb = 0; hb < 2; ++hb) {
        f16x8 hv;
#pragma unroll
        for (int j = 0; j < 8; ++j)
            hv[j] = (_Float16)T[cb + hb * 8 + j][r];
        *(f16x8*)&oh[(size_t)(c0 + r) * MD + r0 + cb + hb * 8] = hv;
    }
}

// ---------------------------------------------------------------- MFMA GEMM, fused A-split, 2-term
// C[M,N] = A32[M,K] @ Bh^T[N,K];  A split to hi/lo in staging, B is f16 hi only.
// mode 0: write f16 row-major; mode 1: write f16 transposed [N][M]; mode 2: fp32 + bias
__global__ __launch_bounds__(256)
void gemm_mfma(const float* __restrict__ A32, const _Float16* __restrict__ Bh,
               _Float16* __restrict__ Of16, float* __restrict__ Cf,
               const float* __restrict__ bias, int M, int N, int K, int mode)
{
    __shared__ _Float16 Ash[64 * LDSTR], Asl[64 * LDSTR], Wsh[64 * LDSTR];

    const int tid  = threadIdx.x;
    const int ln   = tid & 15;
    const int quad = (tid & 63) >> 4;
    const int wv   = tid >> 6;
    const int wr   = wv * 16;
    const int m0   = blockIdx.x * 64;
    const int n0   = blockIdx.y * 64;
    const int srow = tid >> 2;
    const int scol = (tid & 3) << 4;

    f32x4 acc[4] = {{0.f,0.f,0.f,0.f},{0.f,0.f,0.f,0.f},
                    {0.f,0.f,0.f,0.f},{0.f,0.f,0.f,0.f}};

    for (int k0 = 0; k0 < K; k0 += 64) {
        const size_t ga = (size_t)(m0 + srow) * K + k0 + scol;
        const size_t gb = (size_t)(n0 + srow) * K + k0 + scol;
        float a[16];
#pragma unroll
        for (int j = 0; j < 4; ++j) {
            const float4 x = *(const float4*)&A32[ga + j * 4];
            a[j * 4 + 0] = x.x; a[j * 4 + 1] = x.y;
            a[j * 4 + 2] = x.z; a[j * 4 + 3] = x.w;
        }
        const f16x8 b0 = *(const f16x8*)&Bh[gb];
        const f16x8 b1 = *(const f16x8*)&Bh[gb + 8];
        f16x8 ah[2], al[2];
#pragma unroll
        for (int half = 0; half < 2; ++half)
#pragma unroll
            for (int j = 0; j < 8; ++j) {
                const float x = a[half * 8 + j];
                const _Float16 xh = (_Float16)x;
                ah[half][j] = xh;
                al[half][j] = (_Float16)(x - (float)xh);
            }
        __syncthreads();
        *(f16x8*)&Ash[srow * LDSTR + scol]     = ah[0];
        *(f16x8*)&Ash[srow * LDSTR + scol + 8] = ah[1];
        *(f16x8*)&Asl[srow * LDSTR + scol]     = al[0];
        *(f16x8*)&Asl[srow * LDSTR + scol + 8] = al[1];
        *(f16x8*)&Wsh[srow * LDSTR + scol]     = b0;
        *(f16x8*)&Wsh[srow * LDSTR + scol + 8] = b1;
        __syncthreads();

#pragma unroll
        for (int ks = 0; ks < 2; ++ks) {
            const f16x8 fa = *(f16x8*)&Ash[(wr + ln) * LDSTR + ks * 32 + quad * 8];
            const f16x8 fl = *(f16x8*)&Asl[(wr + ln) * LDSTR + ks * 32 + quad * 8];
#pragma unroll
            for (int nt = 0; nt < 4; ++nt) {
                const f16x8 fb = *(f16x8*)&Wsh[(nt * 16 + ln) * LDSTR + ks * 32 + quad * 8];
                acc[nt] = __builtin_amdgcn_mfma_f32_16x16x32_f16(fa, fb, acc[nt], 0, 0, 0);
                acc[nt] = __builtin_amdgcn_mfma_f32_16x16x32_f16(fl, fb, acc[nt], 0, 0, 0);
            }
        }
    }

    if (mode == 0) {
#pragma unroll
        for (int nt = 0; nt < 4; ++nt)
#pragma unroll
            for (int r = 0; r < 4; ++r)
                Of16[(size_t)(m0 + wr + quad * 4 + r) * N + n0 + nt * 16 + ln] =
                    (_Float16)acc[nt][r];
    } else if (mode == 1) {
#pragma unroll
        for (int nt = 0; nt < 4; ++nt)
#pragma unroll
            for (int r = 0; r < 4; ++r)
                Of16[(size_t)(n0 + nt * 16 + ln) * M + m0 + wr + quad * 4 + r] =
                    (_Float16)acc[nt][r];
    } else {
#pragma unroll
        for (int nt = 0; nt < 4; ++nt) {
            const float bb = bias[n0 + nt * 16 + ln];
#pragma unroll
            for (int r = 0; r < 4; ++r)
                Cf[(size_t)(m0 + wr + quad * 4 + r) * N + n0 + nt * 16 + ln] =
                    acc[nt][r] + bb;
        }
    }
}

// ---------------------------------------------------------------- MFMA flash attention
// 256 threads = 4 waves x 64 Q-rows = 256-row block; blockIdx.z = key split (4).
// Pure fp16 QK (1 term), fp16 PV (1 term); no-max softmax (scores bounded).
// Writes UNNORMALIZED partial O (fp16) + partial l.
__global__ __launch_bounds__(256, 2)
void attn_mfma(const _Float16* __restrict__ Qh_g, const _Float16* __restrict__ Kh_g,
               const _Float16* __restrict__ VTh_g, const float* __restrict__ mask,
               _Float16* __restrict__ Opart, float* __restrict__ lpart)
{
    __shared__ _Float16 Kh[64 * LDSTR];    // [key][d]
    __shared__ _Float16 Vh[64 * LDSTR];    // [d][key]
    __shared__ _Float16 Ph[256 * LDSTR];   // [row][key], wave-private rows

    const int tid  = threadIdx.x;
    const int ln   = tid & 15;
    const int quad = (tid & 63) >> 4;
    const int wv   = tid >> 6;           // 0..3
    const int wr   = wv * 64;            // wave row base (0,64,128,192)
    const int h    = blockIdx.y;
    const int m0   = blockIdx.x * 256;
    const int sp   = blockIdx.z;
    const int tbase = sp * KEYS_PER_SPLIT;

    const int srow = tid >> 2;           // 0..63
    const int scol = (tid & 3) << 4;     // 0,16,32,48

    // Q fragments: 4 rowsets x 2 k-chunks (hi only)
    f16x8 qf[4][2];
#pragma unroll
    for (int rs = 0; rs < 4; ++rs)
#pragma unroll
        for (int ks = 0; ks < 2; ++ks)
            qf[rs][ks] = *(const f16x8*)&Qh_g[(size_t)(m0 + wr + rs * 16 + ln) * MD +
                                              h * DH + ks * 32 + quad * 8];

    f32x4 O[4][4];
#pragma unroll
    for (int rs = 0; rs < 4; ++rs)
#pragma unroll
        for (int d = 0; d < 4; ++d)
            O[rs][d] = (f32x4){0.f, 0.f, 0.f, 0.f};
    float lsum[4][4] = {{0.f}};

    const float kSc = 0.125f * 1.4426950408889634f;
    const float kMk = -1e9f * 1.4426950408889634f;

    for (int t = 0; t < KEYS_PER_SPLIT; t += 64) {
        const int t0 = tbase + t;
        // stage K [key][d] and V^T [d][key] (hi only): 2 f16x8 each per thread
        const size_t gk = (size_t)(t0 + srow) * MD + h * DH + scol;
        const size_t gv = (size_t)(h * DH + srow) * SEQ + t0 + scol;
        const f16x8 k0 = *(const f16x8*)&Kh_g[gk];
        const f16x8 k1 = *(const f16x8*)&Kh_g[gk + 8];
        const f16x8 v0 = *(const f16x8*)&VTh_g[gv];
        const f16x8 v1 = *(const f16x8*)&VTh_g[gv + 8];
        __syncthreads();
        *(f16x8*)&Kh[srow * LDSTR + scol]     = k0;
        *(f16x8*)&Kh[srow * LDSTR + scol + 8] = k1;
        *(f16x8*)&Vh[srow * LDSTR + scol]     = v0;
        *(f16x8*)&Vh[srow * LDSTR + scol + 8] = v1;
        __syncthreads();

        // S = Q @ K^T (1 term), B-frags shared across 4 rowsets
        f32x4 s[4][4];
#pragma unroll
        for (int rs = 0; rs < 4; ++rs)
#pragma unroll
            for (int st = 0; st < 4; ++st)
                s[rs][st] = (f32x4){0.f, 0.f, 0.f, 0.f};
#pragma unroll
        for (int st = 0; st < 4; ++st)
#pragma unroll
            for (int ks = 0; ks < 2; ++ks) {
                const f16x8 bh = *(f16x8*)&Kh[(st * 16 + ln) * LDSTR + ks * 32 + quad * 8];
#pragma unroll
                for (int rs = 0; rs < 4; ++rs)
                    s[rs][st] = __builtin_amdgcn_mfma_f32_16x16x32_f16(qf[rs][ks], bh,
                                                                       s[rs][st], 0, 0, 0);
            }

        // softmax numerator (fixed m=0), P -> LDS
#pragma unroll
        for (int rs = 0; rs < 4; ++rs)
#pragma unroll
            for (int st = 0; st < 4; ++st)
#pragma unroll
                for (int r = 0; r < 4; ++r) {
                    const int row = wr + rs * 16 + quad * 4 + r;
                    const float mk = mask[(size_t)(m0 + row) * SEQ + t0 + st * 16 + ln];
                    const float e = exp2f(fmaf(mk, kMk, s[rs][st][r] * kSc));
                    lsum[rs][r] += e;
                    Ph[row * LDSTR + st * 16 + ln] = (_Float16)e;
                }

        // O += P @ V (1 term); wave-private P rows, no barrier
#pragma unroll
        for (int rs = 0; rs < 4; ++rs) {
            f16x8 pa[2];
#pragma unroll
            for (int ks = 0; ks < 2; ++ks)
                pa[ks] = *(f16x8*)&Ph[(wr + rs * 16 + ln) * LDSTR + ks * 32 + quad * 8];
#pragma unroll
            for (int dst = 0; dst < 4; ++dst)
#pragma unroll
                for (int ks = 0; ks < 2; ++ks) {
                    const f16x8 bh = *(f16x8*)&Vh[(dst * 16 + ln) * LDSTR + ks * 32 + quad * 8];
                    O[rs][dst] = __builtin_amdgcn_mfma_f32_16x16x32_f16(pa[ks], bh,
                                                                        O[rs][dst], 0, 0, 0);
                }
        }
    }

    // l reduction across the 16 lanes sharing each row
#pragma unroll
    for (int rs = 0; rs < 4; ++rs)
#pragma unroll
        for (int r = 0; r < 4; ++r)
#pragma unroll
            for (int off = 8; off >= 1; off >>= 1)
                lsum[rs][r] += __shfl_xor(lsum[rs][r], off);

    // epilogue: store UNNORMALIZED partial O (fp16) + partial l
    _Float16* Op = Opart + (size_t)sp * SEQ * MD;
    float*    lp = lpart + ((size_t)sp * NH + h) * SEQ;
#pragma unroll
    for (int rs = 0; rs < 4; ++rs)
#pragma unroll
        for (int r = 0; r < 4; ++r) {
            const int row = m0 + wr + rs * 16 + quad * 4 + r;
            if (ln == 0) lp[row] = lsum[rs][r];
#pragma unroll
            for (int dst = 0; dst < 4; ++dst)
                Op[(size_t)row * MD + h * DH + dst * 16 + ln] = (_Float16)O[rs][dst][r];
        }
}

// ---------------------------------------------------------------- combine: ctx = sum_sp(O)/sum_sp(l) -> fp32
__global__ __launch_bounds__(256)
void combine(const _Float16* __restrict__ Opart, const float* __restrict__ lpart,
             float* __restrict__ Cf)
{
    const size_t NE = (size_t)SEQ * MD;
    const int i = (blockIdx.x * 256 + threadIdx.x) * 4;
    const int row = i >> 9;            // / MD
    const int col = i & (MD - 1);
    const int h   = col >> 6;          // / DH

    float l = 0.f;
#pragma unroll
    for (int sp = 0; sp < NSPLIT; ++sp)
        l += lpart[((size_t)sp * NH + h) * SEQ + row];
    const float inv = 1.0f / l;

    float acc[4] = {0.f, 0.f, 0.f, 0.f};
#pragma unroll
    for (int sp = 0; sp < NSPLIT; ++sp) {
        const f16x4 o = *(const f16x4*)&Opart[sp * NE + i];
#pragma unroll
        for (int j = 0; j < 4; ++j)
            acc[j] += (float)o[j];
    }
    float4 out;
    out.x = acc[0] * inv; out.y = acc[1] * inv;
    out.z = acc[2] * inv; out.w = acc[3] * inv;
    *(float4*)&Cf[i] = out;
}

// ---------------------------------------------------------------- launch
extern "C" void kernel_launch(void* const* d_in, const int* in_sizes, int n_in,
                              void* d_out, int out_size, void* d_ws, size_t ws_size,
                              hipStream_t stream)
{
    const float* q    = (const float*)d_in[0];
    const float* k    = (const float*)d_in[1];
    const float* v    = (const float*)d_in[2];
    const float* mask = (const float*)d_in[3];
    const float* wq   = (const float*)d_in[4];
    const float* wk   = (const float*)d_in[5];
    const float* wv   = (const float*)d_in[6];
    const float* wo   = (const float*)d_in[7];
    const float* bo   = (const float*)d_in[8];
    float* out = (float*)d_out;

    const size_t NE = (size_t)SEQ * MD;   // 2M elements
    const size_t WK = (size_t)MD * MD;    // 256K
    _Float16* base = (_Float16*)d_ws;
    _Float16* Qh    = base;               // NE
    _Float16* Kh    = base + NE;          // NE
    _Float16* VTh   = base + 2 * NE;      // NE  ([MD][SEQ])
    _Float16* Opart = base + 3 * NE;      // 4*NE fp16
    _Float16* wt    = base + 7 * NE;      // 4*WK fp16 (hi only)
    float*    lpart = (float*)(base + 8 * NE);         // NSPLIT*NH*SEQ fp32 (0.5 MB)
    float*    Cf    = (float*)(base + 9 * NE);         // NE fp32 (ctx)

    _Float16* WqT = wt;
    _Float16* WkT = wt + WK;
    _Float16* WvT = wt + 2 * WK;
    _Float16* WoT = wt + 3 * WK;

    // 1. weights: transpose to [N][K] fp16 (hi only), 4 fused
    trans4<<<dim3(MD / 64, MD / 64, 4), 256, 0, stream>>>(wq, wk, wv, wo, wt, WK);

    // 2. projections (A = raw fp32 input, split fused into staging)
    const dim3 gg(SEQ / 64, MD / 64);
    gemm_mfma<<<gg, 256, 0, stream>>>(q, WqT, Qh,  nullptr, nullptr, SEQ, MD, MD, 0);
    gemm_mfma<<<gg, 256, 0, stream>>>(k, WkT, Kh,  nullptr, nullptr, SEQ, MD, MD, 0);
    gemm_mfma<<<gg, 256, 0, stream>>>(v, WvT, VTh, nullptr, nullptr, SEQ, MD, MD, 1);

    // 3. attention, split-K=4 over keys
    attn_mfma<<<dim3(SEQ / 256, NH, NSPLIT), 256, 0, stream>>>(Qh, Kh, VTh, mask,
                                                               Opart, lpart);
    // 4. merge splits -> ctx fp32
    combine<<<(int)(NE / 1024), 256, 0, stream>>>(Opart, lpart, Cf);

    // 5. output projection + bias (ctx split fused into staging)
    gemm_mfma<<<gg, 256, 0, stream>>>(Cf, WoT, nullptr, out, bo, SEQ, MD, MD, 2);
}

// Round 8
// 396.717 us; speedup vs baseline: 1.3765x; 1.3765x over previous
//
#include <hip/hip_runtime.h>
#include <math.h>

#define MD   512
#define NH   8
#define DH   64
#define SEQ  4096
#define NSPLIT 4
#define KEYS_PER_SPLIT (SEQ / NSPLIT)   // 1024

typedef _Float16 f16x8 __attribute__((ext_vector_type(8)));
typedef _Float16 f16x4 __attribute__((ext_vector_type(4)));
typedef float    f32x4 __attribute__((ext_vector_type(4)));

#define LDSTR 72   // f16 row stride: 144 B, 16B-aligned, 2-way bank aliasing max

// ---------------------------------------------------------------- projection GEMM x3 (z-indexed)
// out = in @ W; A fp32 split hi/lo in staging (2-term), W fp32 transposed in staging (hi only).
// z=0: q->Qh (row-major f16), z=1: k->Kh (row-major f16), z=2: v->VTh (transposed [MD][SEQ] f16)
__global__ __launch_bounds__(256)
void proj3(const float* __restrict__ q, const float* __restrict__ k,
           const float* __restrict__ v,
           const float* __restrict__ wq, const float* __restrict__ wk,
           const float* __restrict__ wv,
           _Float16* __restrict__ Qh, _Float16* __restrict__ Kh,
           _Float16* __restrict__ VTh)
{
    const int z = blockIdx.z;
    const float* A32 = (z == 0) ? q : (z == 1) ? k : v;
    const float* W32 = (z == 0) ? wq : (z == 1) ? wk : wv;

    __shared__ _Float16 Ash[64 * LDSTR], Asl[64 * LDSTR], Wsh[64 * LDSTR];

    const int tid  = threadIdx.x;
    const int ln   = tid & 15;
    const int quad = (tid & 63) >> 4;
    const int wv_  = tid >> 6;
    const int wr   = wv_ * 16;
    const int m0   = blockIdx.x * 64;
    const int n0   = blockIdx.y * 64;
    const int srow = tid >> 2;          // 0..63
    const int scol = (tid & 3) << 4;    // 0,16,32,48

    f32x4 acc[4] = {{0.f,0.f,0.f,0.f},{0.f,0.f,0.f,0.f},
                    {0.f,0.f,0.f,0.f},{0.f,0.f,0.f,0.f}};

    for (int k0 = 0; k0 < MD; k0 += 64) {
        // A tile: rows m0+srow, cols k0+scol..+15 (fp32 -> hi/lo)
        const size_t ga = (size_t)(m0 + srow) * MD + k0 + scol;
        // W tile: rows k0+srow (K dim), cols n0+scol..+15 (N dim) -> transposed into Wsh[n][k]
        const size_t gw = (size_t)(k0 + srow) * MD + n0 + scol;
        float a[16], w[16];
#pragma unroll
        for (int j = 0; j < 4; ++j) {
            const float4 xa = *(const float4*)&A32[ga + j * 4];
            a[j*4+0] = xa.x; a[j*4+1] = xa.y; a[j*4+2] = xa.z; a[j*4+3] = xa.w;
            const float4 xw = *(const float4*)&W32[gw + j * 4];
            w[j*4+0] = xw.x; w[j*4+1] = xw.y; w[j*4+2] = xw.z; w[j*4+3] = xw.w;
        }
        f16x8 ah[2], al[2];
#pragma unroll
        for (int half = 0; half < 2; ++half)
#pragma unroll
            for (int j = 0; j < 8; ++j) {
                const float x = a[half * 8 + j];
                const _Float16 xh = (_Float16)x;
                ah[half][j] = xh;
                al[half][j] = (_Float16)(x - (float)xh);
            }
        __syncthreads();
        *(f16x8*)&Ash[srow * LDSTR + scol]     = ah[0];
        *(f16x8*)&Ash[srow * LDSTR + scol + 8] = ah[1];
        *(f16x8*)&Asl[srow * LDSTR + scol]     = al[0];
        *(f16x8*)&Asl[srow * LDSTR + scol + 8] = al[1];
#pragma unroll
        for (int j = 0; j < 16; ++j)
            Wsh[(scol + j) * LDSTR + srow] = (_Float16)w[j];   // transpose scatter
        __syncthreads();

#pragma unroll
        for (int ks = 0; ks < 2; ++ks) {
            const f16x8 fa = *(f16x8*)&Ash[(wr + ln) * LDSTR + ks * 32 + quad * 8];
            const f16x8 fl = *(f16x8*)&Asl[(wr + ln) * LDSTR + ks * 32 + quad * 8];
#pragma unroll
            for (int nt = 0; nt < 4; ++nt) {
                const f16x8 fb = *(f16x8*)&Wsh[(nt * 16 + ln) * LDSTR + ks * 32 + quad * 8];
                acc[nt] = __builtin_amdgcn_mfma_f32_16x16x32_f16(fa, fb, acc[nt], 0, 0, 0);
                acc[nt] = __builtin_amdgcn_mfma_f32_16x16x32_f16(fl, fb, acc[nt], 0, 0, 0);
            }
        }
    }

    if (z == 2) {   // V: write transposed [MD][SEQ]
#pragma unroll
        for (int nt = 0; nt < 4; ++nt)
#pragma unroll
            for (int r = 0; r < 4; ++r)
                VTh[(size_t)(n0 + nt * 16 + ln) * SEQ + m0 + wr + quad * 4 + r] =
                    (_Float16)acc[nt][r];
    } else {
        _Float16* O = (z == 0) ? Qh : Kh;
#pragma unroll
        for (int nt = 0; nt < 4; ++nt)
#pragma unroll
            for (int r = 0; r < 4; ++r)
                O[(size_t)(m0 + wr + quad * 4 + r) * MD + n0 + nt * 16 + ln] =
                    (_Float16)acc[nt][r];
    }
}

// ---------------------------------------------------------------- MFMA flash attention
// 256 threads = 4 waves x 32 Q-rows = 128-row block; blockIdx.z = key split (4).
// Pure fp16 QK + PV (1 term each, R7-validated); no-max softmax.
// Register-safe shape (R7 spill lesson): s[2][4]+O[2][4]+qf[2][2] ~= 96 VGPR.
__global__ __launch_bounds__(256, 4)
void attn_mfma(const _Float16* __restrict__ Qh_g, const _Float16* __restrict__ Kh_g,
               const _Float16* __restrict__ VTh_g, const float* __restrict__ mask,
               _Float16* __restrict__ Opart, float* __restrict__ lpart)
{
    __shared__ _Float16 Kh[64 * LDSTR];    // [key][d]
    __shared__ _Float16 Vh[64 * LDSTR];    // [d][key]
    __shared__ _Float16 Ph[128 * LDSTR];   // [row][key], wave-private rows

    const int tid  = threadIdx.x;
    const int ln   = tid & 15;
    const int quad = (tid & 63) >> 4;
    const int wv   = tid >> 6;           // 0..3
    const int wr   = wv * 32;            // wave row base (0,32,64,96)
    const int h    = blockIdx.y;
    const int m0   = blockIdx.x * 128;
    const int sp   = blockIdx.z;
    const int tbase = sp * KEYS_PER_SPLIT;

    const int srow = tid >> 2;           // 0..63
    const int scol = (tid & 3) << 4;     // 0,16,32,48

    // Q fragments: 2 rowsets x 2 k-chunks (hi only)
    f16x8 qf[2][2];
#pragma unroll
    for (int rs = 0; rs < 2; ++rs)
#pragma unroll
        for (int ks = 0; ks < 2; ++ks)
            qf[rs][ks] = *(const f16x8*)&Qh_g[(size_t)(m0 + wr + rs * 16 + ln) * MD +
                                              h * DH + ks * 32 + quad * 8];

    f32x4 O[2][4];
#pragma unroll
    for (int rs = 0; rs < 2; ++rs)
#pragma unroll
        for (int d = 0; d < 4; ++d)
            O[rs][d] = (f32x4){0.f, 0.f, 0.f, 0.f};
    float lsum[2][4] = {{0.f,0.f,0.f,0.f},{0.f,0.f,0.f,0.f}};

    const float kSc = 0.125f * 1.4426950408889634f;
    const float kMk = -1e9f * 1.4426950408889634f;

    for (int t = 0; t < KEYS_PER_SPLIT; t += 64) {
        const int t0 = tbase + t;
        const size_t gk = (size_t)(t0 + srow) * MD + h * DH + scol;
        const size_t gv = (size_t)(h * DH + srow) * SEQ + t0 + scol;
        const f16x8 k0 = *(const f16x8*)&Kh_g[gk];
        const f16x8 k1 = *(const f16x8*)&Kh_g[gk + 8];
        const f16x8 v0 = *(const f16x8*)&VTh_g[gv];
        const f16x8 v1 = *(const f16x8*)&VTh_g[gv + 8];
        __syncthreads();
        *(f16x8*)&Kh[srow * LDSTR + scol]     = k0;
        *(f16x8*)&Kh[srow * LDSTR + scol + 8] = k1;
        *(f16x8*)&Vh[srow * LDSTR + scol]     = v0;
        *(f16x8*)&Vh[srow * LDSTR + scol + 8] = v1;
        __syncthreads();

        // S = Q @ K^T (1 term), B-frags shared across both rowsets
        f32x4 s[2][4];
#pragma unroll
        for (int rs = 0; rs < 2; ++rs)
#pragma unroll
            for (int st = 0; st < 4; ++st)
                s[rs][st] = (f32x4){0.f, 0.f, 0.f, 0.f};
#pragma unroll
        for (int st = 0; st < 4; ++st)
#pragma unroll
            for (int ks = 0; ks < 2; ++ks) {
                const f16x8 bh = *(f16x8*)&Kh[(st * 16 + ln) * LDSTR + ks * 32 + quad * 8];
#pragma unroll
                for (int rs = 0; rs < 2; ++rs)
                    s[rs][st] = __builtin_amdgcn_mfma_f32_16x16x32_f16(qf[rs][ks], bh,
                                                                       s[rs][st], 0, 0, 0);
            }

        // softmax numerator (fixed m=0), P -> LDS
#pragma unroll
        for (int rs = 0; rs < 2; ++rs)
#pragma unroll
            for (int st = 0; st < 4; ++st)
#pragma unroll
                for (int r = 0; r < 4; ++r) {
                    const int row = wr + rs * 16 + quad * 4 + r;
                    const float mk = mask[(size_t)(m0 + row) * SEQ + t0 + st * 16 + ln];
                    const float e = exp2f(fmaf(mk, kMk, s[rs][st][r] * kSc));
                    lsum[rs][r] += e;
                    Ph[row * LDSTR + st * 16 + ln] = (_Float16)e;
                }

        // O += P @ V (1 term); wave-private P rows, no barrier
        f16x8 pa[2][2];
#pragma unroll
        for (int rs = 0; rs < 2; ++rs)
#pragma unroll
            for (int ks = 0; ks < 2; ++ks)
                pa[rs][ks] = *(f16x8*)&Ph[(wr + rs * 16 + ln) * LDSTR + ks * 32 + quad * 8];
#pragma unroll
        for (int dst = 0; dst < 4; ++dst)
#pragma unroll
            for (int ks = 0; ks < 2; ++ks) {
                const f16x8 bh = *(f16x8*)&Vh[(dst * 16 + ln) * LDSTR + ks * 32 + quad * 8];
#pragma unroll
                for (int rs = 0; rs < 2; ++rs)
                    O[rs][dst] = __builtin_amdgcn_mfma_f32_16x16x32_f16(pa[rs][ks], bh,
                                                                        O[rs][dst], 0, 0, 0);
            }
    }

    // l reduction across the 16 lanes sharing each row
#pragma unroll
    for (int rs = 0; rs < 2; ++rs)
#pragma unroll
        for (int r = 0; r < 4; ++r)
#pragma unroll
            for (int off = 8; off >= 1; off >>= 1)
                lsum[rs][r] += __shfl_xor(lsum[rs][r], off);

    // epilogue: store UNNORMALIZED partial O (fp16) + partial l
    _Float16* Op = Opart + (size_t)sp * SEQ * MD;
    float*    lp = lpart + ((size_t)sp * NH + h) * SEQ;
#pragma unroll
    for (int rs = 0; rs < 2; ++rs)
#pragma unroll
        for (int r = 0; r < 4; ++r) {
            const int row = m0 + wr + rs * 16 + quad * 4 + r;
            if (ln == 0) lp[row] = lsum[rs][r];
#pragma unroll
            for (int dst = 0; dst < 4; ++dst)
                Op[(size_t)row * MD + h * DH + dst * 16 + ln] = (_Float16)O[rs][dst][r];
        }
}

// ---------------------------------------------------------------- output GEMM with fused split-combine
// out = (sum_sp Opart / sum_sp l) @ Wo + bo.  Ctx materialized per A-tile in staging.
__global__ __launch_bounds__(256)
void gemm_out(const _Float16* __restrict__ Opart, const float* __restrict__ lpart,
              const float* __restrict__ Wo, const float* __restrict__ bo,
              float* __restrict__ out)
{
    const size_t NE = (size_t)SEQ * MD;
    __shared__ _Float16 Ash[64 * LDSTR], Asl[64 * LDSTR], Wsh[64 * LDSTR];

    const int tid  = threadIdx.x;
    const int ln   = tid & 15;
    const int quad = (tid & 63) >> 4;
    const int wv_  = tid >> 6;
    const int wr   = wv_ * 16;
    const int m0   = blockIdx.x * 64;
    const int n0   = blockIdx.y * 64;
    const int srow = tid >> 2;
    const int scol = (tid & 3) << 4;

    f32x4 acc[4] = {{0.f,0.f,0.f,0.f},{0.f,0.f,0.f,0.f},
                    {0.f,0.f,0.f,0.f},{0.f,0.f,0.f,0.f}};

    for (int k0 = 0; k0 < MD; k0 += 64) {
        const int row = m0 + srow;
        const int h   = (k0 + scol) >> 6;          // head of this 16-col chunk
        // combine: ctx[row][k0+scol..+15] = sum_sp O / sum_sp l
        float l = 0.f;
#pragma unroll
        for (int sp = 0; sp < NSPLIT; ++sp)
            l += lpart[((size_t)sp * NH + h) * SEQ + row];
        const float inv = 1.0f / l;

        float cx[16] = {0.f};
#pragma unroll
        for (int sp = 0; sp < NSPLIT; ++sp) {
            const size_t go = (size_t)sp * NE + (size_t)row * MD + k0 + scol;
            const f16x8 o0 = *(const f16x8*)&Opart[go];
            const f16x8 o1 = *(const f16x8*)&Opart[go + 8];
#pragma unroll
            for (int j = 0; j < 8; ++j) { cx[j] += (float)o0[j]; cx[8 + j] += (float)o1[j]; }
        }
        // W tile transposed into Wsh[n][k]
        const size_t gw = (size_t)(k0 + srow) * MD + n0 + scol;
        float w[16];
#pragma unroll
        for (int j = 0; j < 4; ++j) {
            const float4 xw = *(const float4*)&Wo[gw + j * 4];
            w[j*4+0] = xw.x; w[j*4+1] = xw.y; w[j*4+2] = xw.z; w[j*4+3] = xw.w;
        }
        f16x8 ah[2], al[2];
#pragma unroll
        for (int half = 0; half < 2; ++half)
#pragma unroll
            for (int j = 0; j < 8; ++j) {
                const float x = cx[half * 8 + j] * inv;
                const _Float16 xh = (_Float16)x;
                ah[half][j] = xh;
                al[half][j] = (_Float16)(x - (float)xh);
            }
        __syncthreads();
        *(f16x8*)&Ash[srow * LDSTR + scol]     = ah[0];
        *(f16x8*)&Ash[srow * LDSTR + scol + 8] = ah[1];
        *(f16x8*)&Asl[srow * LDSTR + scol]     = al[0];
        *(f16x8*)&Asl[srow * LDSTR + scol + 8] = al[1];
#pragma unroll
        for (int j = 0; j < 16; ++j)
            Wsh[(scol + j) * LDSTR + srow] = (_Float16)w[j];
        __syncthreads();

#pragma unroll
        for (int ks = 0; ks < 2; ++ks) {
            const f16x8 fa = *(f16x8*)&Ash[(wr + ln) * LDSTR + ks * 32 + quad * 8];
            const f16x8 fl = *(f16x8*)&Asl[(wr + ln) * LDSTR + ks * 32 + quad * 8];
#pragma unroll
            for (int nt = 0; nt < 4; ++nt) {
                const f16x8 fb = *(f16x8*)&Wsh[(nt * 16 + ln) * LDSTR + ks * 32 + quad * 8];
                acc[nt] = __builtin_amdgcn_mfma_f32_16x16x32_f16(fa, fb, acc[nt], 0, 0, 0);
                acc[nt] = __builtin_amdgcn_mfma_f32_16x16x32_f16(fl, fb, acc[nt], 0, 0, 0);
            }
        }
    }

#pragma unroll
    for (int nt = 0; nt < 4; ++nt) {
        const float bb = bo[n0 + nt * 16 + ln];
#pragma unroll
        for (int r = 0; r < 4; ++r)
            out[(size_t)(m0 + wr + quad * 4 + r) * MD + n0 + nt * 16 + ln] =
                acc[nt][r] + bb;
    }
}

// ---------------------------------------------------------------- launch
extern "C" void kernel_launch(void* const* d_in, const int* in_sizes, int n_in,
                              void* d_out, int out_size, void* d_ws, size_t ws_size,
                              hipStream_t stream)
{
    const float* q    = (const float*)d_in[0];
    const float* k    = (const float*)d_in[1];
    const float* v    = (const float*)d_in[2];
    const float* mask = (const float*)d_in[3];
    const float* wq   = (const float*)d_in[4];
    const float* wk   = (const float*)d_in[5];
    const float* wv   = (const float*)d_in[6];
    const float* wo   = (const float*)d_in[7];
    const float* bo   = (const float*)d_in[8];
    float* out = (float*)d_out;

    const size_t NE = (size_t)SEQ * MD;   // 2M elements
    _Float16* base = (_Float16*)d_ws;
    _Float16* Qh    = base;               // NE
    _Float16* Kh    = base + NE;          // NE
    _Float16* VTh   = base + 2 * NE;      // NE ([MD][SEQ])
    _Float16* Opart = base + 3 * NE;      // NSPLIT*NE fp16
    float*    lpart = (float*)(base + (3 + NSPLIT) * NE);  // NSPLIT*NH*SEQ fp32

    // 1. q/k/v projections (one dispatch; weight transpose + input split fused)
    proj3<<<dim3(SEQ / 64, MD / 64, 3), 256, 0, stream>>>(q, k, v, wq, wk, wv,
                                                          Qh, Kh, VTh);

    // 2. attention, split-K=4 over keys
    attn_mfma<<<dim3(SEQ / 128, NH, NSPLIT), 256, 0, stream>>>(Qh, Kh, VTh, mask,
                                                               Opart, lpart);

    // 3. output projection (combine + bias fused)
    gemm_out<<<dim3(SEQ / 64, MD / 64), 256, 0, stream>>>(Opart, lpart, wo, bo, out);
}